// Round 4
// baseline (5188.951 us; speedup 1.0000x reference)
//
#include <hip/hip_runtime.h>
#include <cmath>

#define SEQ 512
#define BATCH 2048
#define DIM 64
#define HID 128
#define SB (BATCH * DIM)   // x stride per timestep (floats)

// Round-12: r11 architecture unchanged. ONE change: pin the occupancy range
// with amdgpu_waves_per_eu(3,3). r11's __launch_bounds__(256,3) only set the
// MINIMUM waves/EU; the allocator targeted 6 waves/EU (VGPR_Count=84=512/6)
// and spilled ~33 regs/thread (WRITE_SIZE 70.6 MB = once-written scratch,
// reloads L2-absorbed, VALUBusy 16% = scratch-latency-bound). min=max=3
// forces the 168-VGPR budget; demand ~140 fits with headroom.

#define R8(M) M(0) M(1) M(2) M(3) M(4) M(5) M(6) M(7)
#define R16(M) R8(M) M(8) M(9) M(10) M(11) M(12) M(13) M(14) M(15)

#define PIN4(F_) asm volatile("" : "+v"(F_.x), "+v"(F_.y), "+v"(F_.z), "+v"(F_.w));
#define PIN1(F_) asm volatile("" : "+v"(F_));

__device__ __forceinline__ float fast_tanh(float z) {
    // tanh(z) = 1 - 2/(exp(2z)+1); v_exp + v_rcp, exact saturation both ends.
    const float e = __expf(2.0f * z);
    return 1.0f - 2.0f * __builtin_amdgcn_rcpf(e + 1.0f);
}

__global__ __launch_bounds__(256)
__attribute__((amdgpu_waves_per_eu(3, 3)))
void rnn_kernel(const float* __restrict__ x,
                const float* __restrict__ h0,
                const float* __restrict__ W_ih,
                const float* __restrict__ b_ih,
                const float* __restrict__ W_hh,
                const float* __restrict__ b_hh,
                float* __restrict__ out) {
    __shared__ __align__(16) float xs[2][4][64];    // 2 groups x 4 steps x 64 x-vals
    __shared__ __align__(16) float part1[2][HID];   // GEMM1 k-half partials
    __shared__ __align__(16) float part2[2][HID];   // GEMM2 k-half partials
    __shared__ __align__(16) float act[HID];        // wihx broadcast tile

    const int tid = threadIdx.x;
    const int b = blockIdx.x;
    const int j = tid & 127;          // hidden index (two waves per kh-half)
    const int kh = tid >> 7;          // k-half owner: 0 or 1 (wave-uniform)
    const int lane = tid & 63;

    // ---- pinned weight slices: W_ih[j][kh*32 .. +32), W_hh[j][kh*64 .. +64) ----
    const float4* wip = (const float4*)(W_ih + j * DIM + kh * 32);
#define DECL_WI(i) float4 wi##i = wip[i]; PIN4(wi##i)
    R8(DECL_WI)
    const float4* whp = (const float4*)(W_hh + j * HID + kh * 64);
#define DECL_WH(i) float4 wh##i = whp[i]; PIN4(wh##i)
    R16(DECL_WH)

    float bi = b_ih[j];  PIN1(bi)
    float bh = b_hh[j];  PIN1(bh)
    float h = h0[b * HID + j];        // live state on kh==0 threads only

    // ---- x staging: lane L covers step (L>>4), floats (L&15)*4 .. +4 ----
    const float* xgl = x + (size_t)b * DIM + (size_t)(lane >> 4) * SB
                         + (size_t)((lane & 15) * 4);
    float* xlds = &xs[0][lane >> 4][(lane & 15) * 4];  // buffer stride = 256 floats

    *(float4*)(xlds)       = *(const float4*)(xgl);                  // group 0
    *(float4*)(xlds + 256) = *(const float4*)(xgl + 4 * (size_t)SB); // group 1
    float4 xr = *(const float4*)(xgl + 8 * (size_t)SB);  // group 2 in flight
    const float* xnext = xgl + 12 * (size_t)SB;

    // ---- prologue: produce act(0) ----
    float wihx = 0.0f;
    {
        float pP = 0.f, pQ = 0.f;
        const float4* xv = (const float4*)&xs[0][0][kh * 32];
#define G1P(c) { const float4 v_ = xv[c]; \
        pP += wi##c.x * v_.x; pP += wi##c.y * v_.y; \
        pQ += wi##c.z * v_.z; pQ += wi##c.w * v_.w; }
        R8(G1P)
        part1[kh][j] = pP + pQ;
    }
    asm volatile("s_waitcnt lgkmcnt(0)\n\ts_barrier" ::: "memory");
    if (kh == 0) {
        wihx = ((part1[0][j] + part1[1][j]) + bi) * h;
        act[j] = wihx;
    }
    asm volatile("s_waitcnt lgkmcnt(0)\n\ts_barrier" ::: "memory");

#pragma unroll 1
    for (int t = 0; t < SEQ; ++t) {
        // group boundary: commit the in-flight group (covering t+5..t+8) to
        // LDS and issue the load for the next one.
        if ((t & 3) == 3) {
            if (t + 5 < SEQ) {
                *(float4*)(xlds + ((t >> 2) & 1) * 256) = xr;  // waits xr's vmcnt
                if (t + 9 < SEQ) {
                    xr = *(const float4*)xnext;
                    xnext += 4 * (size_t)SB;
                }
            }
        }

        // ---- X: GEMM2(t) own k-half + GEMM1(t+1) partial (independent chains) ----
        float qP = 0.f, qQ = 0.f;
        const float4* av = (const float4*)&act[kh * 64];
#define G2P(c) { const float4 v_ = av[c]; \
        qP += wh##c.x * v_.x; qP += wh##c.y * v_.y; \
        qQ += wh##c.z * v_.z; qQ += wh##c.w * v_.w; }
        R16(G2P)

        const int tn = t + 1;
        if (tn < SEQ) {          // GEMM1 is non-recurrent: compute next step's
            float pP = 0.f, pQ = 0.f;  // partials under GEMM2's region
            const float4* xv = (const float4*)&xs[(tn >> 2) & 1][tn & 3][kh * 32];
#define G1N(c) { const float4 v_ = xv[c]; \
            pP += wi##c.x * v_.x; pP += wi##c.y * v_.y; \
            pQ += wi##c.z * v_.z; pQ += wi##c.w * v_.w; }
            R8(G1N)
            part1[kh][j] = pP + pQ;
        }
        part2[kh][j] = qP + qQ;
        asm volatile("s_waitcnt lgkmcnt(0)\n\ts_barrier" ::: "memory");  // B_odd

        // ---- Y: scalar tail on kh==0 waves only ----
        if (kh == 0) {
            const float whh = ((part2[0][j] + part2[1][j]) + bh) * h;
            h = fast_tanh(wihx + whh);
            if (tn < SEQ) {
                wihx = ((part1[0][j] + part1[1][j]) + bi) * h;
                act[j] = wihx;
            }
        }
        asm volatile("s_waitcnt lgkmcnt(0)\n\ts_barrier" ::: "memory");  // B_even
        // act/part single-buffered is safe: read X(t) / write Y(t) split by
        // B_odd; write Y(t) / read X(t+1) split by B_even.
    }

    if (kh == 0) out[b * HID + j] = h;
}

extern "C" void kernel_launch(void* const* d_in, const int* in_sizes, int n_in,
                              void* d_out, int out_size, void* d_ws, size_t ws_size,
                              hipStream_t stream) {
    const float* x    = (const float*)d_in[0];
    const float* h0   = (const float*)d_in[1];
    const float* W_ih = (const float*)d_in[2];
    const float* b_ih = (const float*)d_in[3];
    const float* W_hh = (const float*)d_in[4];
    const float* b_hh = (const float*)d_in[5];
    float* out = (float*)d_out;

    dim3 grid(BATCH);       // one batch element per block
    dim3 block(256);        // 4 waves: (j 0..127) x (k-half 0..1)
    rnn_kernel<<<grid, block, 0, stream>>>(x, h0, W_ih, b_ih, W_hh, b_hh, out);
}

// Round 5
// 1781.345 us; speedup vs baseline: 2.9129x; 2.9129x over previous
//
#include <hip/hip_runtime.h>
#include <cmath>

#define SEQ 512
#define BATCH 2048
#define DIM 64
#define HID 128
#define SB (BATCH * DIM)   // x stride per timestep (floats)

// Round-13: structural fix for the r10-r12 spill saga. The allocator insists
// on an 84-VGPR budget (VGPR_Count=84 across (256,3) and waves_per_eu(3,3);
// WRITE_SIZE 70.6 MB = ~33 spilled weight floats written once + L2-resident
// reloads; VALUBusy 16%). Instead of fighting it: 4-way k-split, 512 threads.
//   kq = tid>>7 (k-quarter), j = tid&127.
//   Per-thread pinned weights: W_ih[j][kq*16..+16) = 4 float4,
//                              W_hh[j][kq*32..+32) = 8 float4  -> 48 floats.
//   Total demand ~79 regs < 84 -> nothing to spill even if attrs are ignored.
// Everything else keeps the proven r11 scheme: wave-uniform ds_read_b128
// operand broadcast, GEMM1(t+1) interleaved under GEMM2(t), two lgkm-only
// barriers/step, reg-staged x -> LDS once per 4 steps, scalar tail (combine 4
// partials + tanh) on kq==0 waves only (wave-uniform branch).

#define R4(M) M(0) M(1) M(2) M(3)
#define R8(M) R4(M) M(4) M(5) M(6) M(7)

#define PIN4(F_) asm volatile("" : "+v"(F_.x), "+v"(F_.y), "+v"(F_.z), "+v"(F_.w));
#define PIN1(F_) asm volatile("" : "+v"(F_));

__device__ __forceinline__ float fast_tanh(float z) {
    // tanh(z) = 1 - 2/(exp(2z)+1); v_exp + v_rcp, exact saturation both ends.
    const float e = __expf(2.0f * z);
    return 1.0f - 2.0f * __builtin_amdgcn_rcpf(e + 1.0f);
}

__global__ __launch_bounds__(512)
__attribute__((amdgpu_waves_per_eu(4, 6)))
void rnn_kernel(const float* __restrict__ x,
                const float* __restrict__ h0,
                const float* __restrict__ W_ih,
                const float* __restrict__ b_ih,
                const float* __restrict__ W_hh,
                const float* __restrict__ b_hh,
                float* __restrict__ out) {
    __shared__ __align__(16) float xs[2][4][64];    // 2 groups x 4 steps x 64 x-vals
    __shared__ __align__(16) float part1[4][HID];   // GEMM1 k-quarter partials
    __shared__ __align__(16) float part2[4][HID];   // GEMM2 k-quarter partials
    __shared__ __align__(16) float act[HID];        // wihx broadcast tile

    const int tid = threadIdx.x;
    const int b = blockIdx.x;
    const int j = tid & 127;          // hidden index
    const int kq = tid >> 7;          // k-quarter owner 0..3 (wave-uniform)
    const int lane = tid & 63;

    // ---- pinned weight slices ----
    const float4* wip = (const float4*)(W_ih + j * DIM + kq * 16);
#define DECL_WI(i) float4 wi##i = wip[i]; PIN4(wi##i)
    R4(DECL_WI)
    const float4* whp = (const float4*)(W_hh + j * HID + kq * 32);
#define DECL_WH(i) float4 wh##i = whp[i]; PIN4(wh##i)
    R8(DECL_WH)

    float bi = b_ih[j];  PIN1(bi)
    float bh = b_hh[j];  PIN1(bh)
    float h = h0[b * HID + j];        // meaningful on kq==0 threads only

    // ---- x staging: lane L covers step (L>>4), floats (L&15)*4 .. +4 ----
    // (all 8 waves redundantly stage identical bytes; benign same-byte races)
    const float* xgl = x + (size_t)b * DIM + (size_t)(lane >> 4) * SB
                         + (size_t)((lane & 15) * 4);
    float* xlds = &xs[0][lane >> 4][(lane & 15) * 4];  // buffer stride = 256 floats

    *(float4*)(xlds)       = *(const float4*)(xgl);                  // group 0
    *(float4*)(xlds + 256) = *(const float4*)(xgl + 4 * (size_t)SB); // group 1
    float4 xr = *(const float4*)(xgl + 8 * (size_t)SB);  // group 2 in flight
    const float* xnext = xgl + 12 * (size_t)SB;

    // ---- prologue: produce act(0) ----
    float wihx = 0.0f;
    {
        float pP = 0.f, pQ = 0.f;
        const float4* xv = (const float4*)&xs[0][0][kq * 16];
#define G1P(c) { const float4 v_ = xv[c]; \
        pP += wi##c.x * v_.x; pP += wi##c.y * v_.y; \
        pQ += wi##c.z * v_.z; pQ += wi##c.w * v_.w; }
        R4(G1P)
        part1[kq][j] = pP + pQ;
    }
    asm volatile("s_waitcnt lgkmcnt(0)\n\ts_barrier" ::: "memory");
    if (kq == 0) {
        wihx = (((part1[0][j] + part1[1][j]) + (part1[2][j] + part1[3][j])) + bi) * h;
        act[j] = wihx;
    }
    asm volatile("s_waitcnt lgkmcnt(0)\n\ts_barrier" ::: "memory");

#pragma unroll 1
    for (int t = 0; t < SEQ; ++t) {
        // group boundary: commit the in-flight group (covering t+5..t+8) to
        // LDS and issue the load for the next one.
        if ((t & 3) == 3) {
            if (t + 5 < SEQ) {
                *(float4*)(xlds + ((t >> 2) & 1) * 256) = xr;  // waits xr's vmcnt
                if (t + 9 < SEQ) {
                    xr = *(const float4*)xnext;
                    xnext += 4 * (size_t)SB;
                }
            }
        }

        // ---- X: GEMM2(t) own k-quarter + GEMM1(t+1) quarter ----
        float qP = 0.f, qQ = 0.f;
        const float4* av = (const float4*)&act[kq * 32];
#define G2P(c) { const float4 v_ = av[c]; \
        qP += wh##c.x * v_.x; qP += wh##c.y * v_.y; \
        qQ += wh##c.z * v_.z; qQ += wh##c.w * v_.w; }
        R8(G2P)

        const int tn = t + 1;
        if (tn < SEQ) {          // GEMM1 is non-recurrent: next step's partial
            float pP = 0.f, pQ = 0.f;
            const float4* xv = (const float4*)&xs[(tn >> 2) & 1][tn & 3][kq * 16];
#define G1N(c) { const float4 v_ = xv[c]; \
            pP += wi##c.x * v_.x; pP += wi##c.y * v_.y; \
            pQ += wi##c.z * v_.z; pQ += wi##c.w * v_.w; }
            R4(G1N)
            part1[kq][j] = pP + pQ;
        }
        part2[kq][j] = qP + qQ;
        asm volatile("s_waitcnt lgkmcnt(0)\n\ts_barrier" ::: "memory");  // B_odd

        // ---- Y: scalar tail on kq==0 waves only (wave-uniform branch) ----
        if (kq == 0) {
            const float whh = (((part2[0][j] + part2[1][j])
                              + (part2[2][j] + part2[3][j])) + bh) * h;
            h = fast_tanh(wihx + whh);
            if (tn < SEQ) {
                wihx = (((part1[0][j] + part1[1][j])
                       + (part1[2][j] + part1[3][j])) + bi) * h;
                act[j] = wihx;
            }
        }
        asm volatile("s_waitcnt lgkmcnt(0)\n\ts_barrier" ::: "memory");  // B_even
        // act/part single-buffered is safe: read X(t) / write Y(t) split by
        // B_odd; write Y(t) / read X(t+1) split by B_even.
    }

    if (kq == 0) out[b * HID + j] = h;
}

extern "C" void kernel_launch(void* const* d_in, const int* in_sizes, int n_in,
                              void* d_out, int out_size, void* d_ws, size_t ws_size,
                              hipStream_t stream) {
    const float* x    = (const float*)d_in[0];
    const float* h0   = (const float*)d_in[1];
    const float* W_ih = (const float*)d_in[2];
    const float* b_ih = (const float*)d_in[3];
    const float* W_hh = (const float*)d_in[4];
    const float* b_hh = (const float*)d_in[5];
    float* out = (float*)d_out;

    dim3 grid(BATCH);       // one batch element per block
    dim3 block(512);        // 8 waves: (j 0..127) x (k-quarter 0..3)
    rnn_kernel<<<grid, block, 0, stream>>>(x, h0, W_ih, b_ih, W_hh, b_hh, out);
}